// Round 14
// baseline (333.696 us; speedup 1.0000x reference)
//
#include <hip/hip_runtime.h>
#include <hip/hip_fp16.h>

typedef _Float16 f16x8 __attribute__((ext_vector_type(8)));
typedef float f32x4 __attribute__((ext_vector_type(4)));

union U4H8 { uint4 u; f16x8 h; };
__device__ inline f16x8 asH(uint4 u){ U4H8 x; x.u = u; return x.h; }
__device__ inline unsigned int pk(float a, float b){
    __half2 h = __floats2half2_rn(a, b);
    union { __half2 h; unsigned int u; } c; c.h = h; return c.u;
}
__device__ inline unsigned int pkr(float a, float b){
    return pk(fmaxf(a, 0.f), fmaxf(b, 0.f));
}
__device__ inline unsigned short h16(float a){
    union { __half h; unsigned short s; } c; c.h = __float2half(a); return c.s;
}

// ws dword layout: frags uint4[28][64] = dwords [0,7168);
// b1f f32[16][64] @7168 | b2f f32[4][64] @8192 | b3f f32[8][64] @8448 |
// b4f f32[4][64] @8960 ; end 9216 dwords (36 KiB).
#define NFRAG 28
#define WS_B1 7168
#define WS_B2 8192
#define WS_B3 8448
#define WS_B4 8960

// frag fi: 0-1 conv1 (k=kh*8+kw, rows=oc); 2-14 conv2 (k=tap*16+ic, rows=oc);
//          15-26 fc1 (nt*6+kk, k=pos*12+oc2, rows=fc-col); 27 fc2 (rows=logit)
__global__ __launch_bounds__(256) void build_tables(
    const float* __restrict__ H1w, const float* __restrict__ H1b,
    const float* __restrict__ H2w, const float* __restrict__ H2b,
    const float* __restrict__ H3w, const float* __restrict__ H3b,
    const float* __restrict__ outw, const float* __restrict__ outb,
    unsigned int* __restrict__ ws)
{
    const int t = threadIdx.x, b = blockIdx.x;
    float* wsf = (float*)ws;

    if (b < NFRAG) {
        if (t < 64) {
            const int lane = t, ch = lane >> 4, oc = lane & 15;
            const int fi = b;
            unsigned short us[8];
            for (int j = 0; j < 8; ++j) {
                float w = 0.f;
                if (fi < 2) {                         // conv1
                    int kh = fi * 4 + ch;
                    if (kh < 5 && j < 5 && oc < 12) w = H1w[oc * 25 + kh * 5 + j];
                } else if (fi < 15) {                 // conv2 channels-last
                    int kk = fi - 2;
                    int tap = kk * 2 + (ch >> 1);
                    int ic = (ch & 1) * 8 + j;
                    if (tap < 25 && oc < 12) {
                        int kh = tap / 5, kw = tap % 5;
                        int q = oc >> 2, icl = -1;
                        if (q == 0)      { if (ic < 8) icl = ic; }
                        else if (q == 1) { if (ic >= 4 && ic < 12) icl = ic - 4; }
                        else             { if (ic < 4) icl = ic;
                                           else if (ic >= 8 && ic < 12) icl = ic - 4; }
                        if (icl >= 0) w = H2w[((oc * 8 + icl) * 5 + kh) * 5 + kw];
                    }
                } else if (fi < 27) {                 // fc1 (k = pos*12+oc2)
                    int idx = fi - 15, nt = idx / 6, kk = idx % 6;
                    int k = kk * 32 + ch * 8 + j;     // 0..191
                    int pos = k / 12, oc2 = k % 12;
                    int col = nt * 16 + oc;
                    if (col < 30) w = H3w[(oc2 * 16 + pos) * 30 + col];
                } else {                              // fc2
                    int k = ch * 8 + j;
                    if (k < 30 && oc < 10) w = outw[k * 10 + oc];
                }
                us[j] = h16(w);
            }
            uint4 u;
            u.x = us[0] | ((unsigned int)us[1] << 16);
            u.y = us[2] | ((unsigned int)us[3] << 16);
            u.z = us[4] | ((unsigned int)us[5] << 16);
            u.w = us[6] | ((unsigned int)us[7] << 16);
            ((uint4*)ws)[fi * 64 + lane] = u;
        }
    } else if (b == NFRAG) {        // b1f: entry e=tt*4+r, lane(ch,m); oc=4ch+r
        for (int idx = t; idx < 1024; idx += 256) {
            int e = idx >> 6, l2 = idx & 63;
            int tt = e >> 2, r = e & 3;
            int oc = 4 * (l2 >> 4) + r, m2 = l2 & 15;
            int oh = 2 * tt + (m2 >> 3), ow = m2 & 7;
            float v = 0.f;
            if (oc < 12) {
                v = H1b[oc * 64 + oh * 8 + ow];
                for (int kh = 0; kh < 5; ++kh)
                    for (int kw = 0; kw < 5; ++kw) {
                        int rr = 2 * oh + kh, cc = 2 * ow + kw;
                        if (rr < 2 || rr >= 18 || cc < 2 || cc >= 18)
                            v -= H1w[oc * 25 + kh * 5 + kw];
                    }
            }
            wsf[WS_B1 + e * 64 + l2] = v;
        }
    } else {                        // b2f + b3f + b4f
        {
            int e = t >> 6, l2 = t & 63;
            int oc = 4 * (l2 >> 4) + e, m2 = l2 & 15;
            int oh = m2 >> 2, ow = m2 & 3;
            float v = 0.f;
            if (oc < 12) {
                v = H2b[oc * 16 + oh * 4 + ow];
                for (int icl = 0; icl < 8; ++icl)
                    for (int kh = 0; kh < 5; ++kh)
                        for (int kw = 0; kw < 5; ++kw) {
                            int rr = 2 * oh + kh - 2, cc = 2 * ow + kw - 2;
                            if (rr < 0 || rr >= 8 || cc < 0 || cc >= 8)
                                v -= H2w[((oc * 8 + icl) * 5 + kh) * 5 + kw];
                        }
            }
            wsf[WS_B2 + e * 64 + l2] = v;
        }
        for (int i = t; i < 512; i += 256) {    // b3f: e = nt*4+r
            int e = i >> 6, l2 = i & 63;
            int nt = e >> 2, r = e & 3, ch = l2 >> 4;
            int j = nt * 16 + 4 * ch + r;
            wsf[WS_B3 + e * 64 + l2] = (j < 30) ? H3b[j] : 0.f;
        }
        {                                        // b4f: e = r
            int e = t >> 6, l2 = t & 63, ch = l2 >> 4;
            int j = 4 * ch + e;
            wsf[WS_B4 + e * 64 + l2] = (j < 10) ? outb[j] : 0.f;
        }
    }
}

// ---------------- main kernel: 512 threads, 16 samples, 8 waves ----------------
// conv1 A-fragments are built DIRECTLY from global x (4x float2 + cvt_pk +
// cndmask zero-fill per fragment) — no xs staging in LDS at all. The pad-fold
// biases (b1f) already encode pad=-1 as "stored 0 + bias adjustment", so
// zero-masking pad rows/cols reproduces the padded conv exactly. Addresses
// are clamped to [0,254] within the sample (masked lanes read junk safely).
// LDS (44032 B -> 3 blocks/CU):
//   wave h1c region @ w*4608: [144 pos][16 ch] half, XOR-swizzled (R8 layout).
//     Ring zeroed ONCE per block (nothing overwrites ring positions now).
//   h2 @ 36864: 16 slots x 384 B, XOR-swizzled by slot&7
//   h3 @ 43008: 16 slots x 64 B, XOR by sample&3
// launch_bounds (512,4): cap 128 VGPR (R10: tighter caps -> catastrophic spill).
#define H2B 36864
#define H3B 43008
__global__ __launch_bounds__(512, 4) void modernnet_mfma(
    const float* __restrict__ x, const unsigned int* __restrict__ ws,
    float* __restrict__ out)
{
    __shared__ uint4 lds4[2752];
    char* L = (char*)lds4;
    const int t = threadIdx.x, wave = t >> 6, l = t & 63;
    const int ch = l >> 4, m = l & 15;
    char* base = L + wave * 4608;
    const int sblk = blockIdx.x * 16;
    const int s0 = sblk + wave * 2;

    const uint4* fr = (const uint4*)ws;
    const float* wsf = (const float*)ws;

    // conv1 weight + bias frags
    uint4 c1b0 = fr[0 * 64 + l], c1b1 = fr[1 * 64 + l];
    f32x4 b1f[4];
    #pragma unroll
    for (int tt = 0; tt < 4; ++tt)
        #pragma unroll
        for (int r = 0; r < 4; ++r) b1f[tt][r] = wsf[WS_B1 + (tt * 4 + r) * 64 + l];

    // conv2 per-lane read offsets (16-ch swizzled layout, R8-proven)
    int c2off[13];
    {
        const int mb = 24 * (m >> 2) + 2 * (m & 3);
        const int hb = (ch & 1) << 4;
        const int sel = (ch >> 1) & 1;
        #pragma unroll
        for (int kk = 0; kk < 13; ++kk) {
            const int t0 = 2 * kk;
            const int t1 = (2 * kk + 1 <= 24) ? 2 * kk + 1 : 24;
            const int p0 = (t0 / 5) * 12 + (t0 % 5);
            const int p1 = (t1 / 5) * 12 + (t1 % 5);
            int pos = mb + (sel ? p1 : p0);
            c2off[kk] = ((pos << 5) + hb) ^ ((pos & 12) << 2);
        }
    }

    // conv2 weights + bias
    uint4 c2b[13];
    #pragma unroll
    for (int kk = 0; kk < 13; ++kk) c2b[kk] = fr[(2 + kk) * 64 + l];
    f32x4 b2f;
    #pragma unroll
    for (int r = 0; r < 4; ++r) b2f[r] = wsf[WS_B2 + r * 64 + l];

    // zero h1c pad ring ONCE (interior epi writes never touch ring positions)
    {
        uint4 z; z.x = z.y = z.z = z.w = 0u;
        #pragma unroll
        for (int k2 = 0; k2 < 3; ++k2) {
            int idx = l + k2 * 64;          // 0..159
            if (idx < 160) {
                int pi = idx >> 1, half = idx & 1;
                int pos;
                if (pi < 24) pos = pi;
                else if (pi < 48) pos = pi + 96;
                else {
                    int q = pi - 48;
                    int c = q & 3; c = (c < 2) ? c : c + 8;
                    pos = (2 + (q >> 2)) * 12 + c;
                }
                int off = ((pos << 5) + (half << 4)) ^ ((pos & 12) << 2);
                *(uint4*)(base + off) = z;
            }
        }
    }

    // per-lane conv1 geometry: fragment = 8 cols [c0..c0+7] of padded row r
    const int h2r = 2 * (m >> 3);           // 2h
    const int c0 = 2 * (m & 7);             // 0..14 (even)
    bool cok[4];
    #pragma unroll
    for (int p = 0; p < 4; ++p) {
        int cA = c0 + 2 * p;                // even; pair (cA,cA+1) valid iff
        cok[p] = (cA >= 2) && (cA <= 16);   // 2<=cA && cA+1<=17
    }

    // -------- two sample passes through the single h1c region --------
    #pragma unroll
    for (int s = 0; s < 2; ++s) {
        const float* xg = x + (size_t)(s0 + s) * 256;

        // conv1 fragments direct from global (fp32 -> f16, pad zero-masked)
        uint4 rd[5];
        #pragma unroll
        for (int i = 0; i < 5; ++i) {
            const int r = 4 * i + h2r + ch;              // padded row 0..21
            const bool rok = (r >= 2) && (r <= 17);
            const int gb = (r - 2) * 16 + (c0 - 2);
            unsigned int wd[4];
            #pragma unroll
            for (int p = 0; p < 4; ++p) {
                int gi = gb + 2 * p;
                gi = gi < 0 ? 0 : (gi > 254 ? 254 : gi);  // clamp in-sample
                float2 v = *(const float2*)(xg + gi);
                const bool ok = rok && cok[p];
                wd[p] = ok ? pk(v.x, v.y) : 0u;
            }
            rd[i] = make_uint4(wd[0], wd[1], wd[2], wd[3]);
        }

        // conv1: tile tt uses rd[tt] (kh0-3) + rd[tt+1] (kh4; only ch=0 lanes
        // carry nonzero c1b1 weights, their rows = 4tt+2h+4 = correct kh4 row)
        f32x4 acc1[4];
        #pragma unroll
        for (int tt = 0; tt < 4; ++tt) {
            f32x4 acc = b1f[tt];
            acc = __builtin_amdgcn_mfma_f32_16x16x32_f16(asH(c1b0), asH(rd[tt]), acc, 0, 0, 0);
            acc = __builtin_amdgcn_mfma_f32_16x16x32_f16(asH(c1b1), asH(rd[tt + 1]), acc, 0, 0, 0);
            acc1[tt] = acc;
        }

        // conv1 epilogue: rows=oc in regs, col=pos -> b64 swizzled writes.
        // (pass-1 writes queue after pass-0 conv2 reads: same-wave LDS order)
        #pragma unroll
        for (int tt = 0; tt < 4; ++tt) {
            const int pos = (2 * tt + (m >> 3) + 2) * 12 + (m & 7) + 2;
            const int off = ((pos << 5) + ch * 8) ^ ((pos & 12) << 2);
            unsigned int w0 = pkr(acc1[tt][0], acc1[tt][1]);
            unsigned int w1 = pkr(acc1[tt][2], acc1[tt][3]);
            *(uint2*)(base + off) = make_uint2(w0, w1);
        }

        // conv2: 13 b128 reads + 13 MFMA; h2 write XOR-swizzled by slot
        {
            f32x4 a = b2f;
            #pragma unroll
            for (int kk = 0; kk < 13; ++kk) {
                uint4 r0 = *(const uint4*)(base + c2off[kk]);
                a = __builtin_amdgcn_mfma_f32_16x16x32_f16(asH(c2b[kk]), asH(r0), a, 0, 0, 0);
            }
            if (ch < 3) {
                const int slot = wave * 2 + s;
                const int off = m * 24 + ch * 8;
                unsigned int w0 = pkr(a[0], a[1]);
                unsigned int w1 = pkr(a[2], a[3]);
                *(uint2*)(L + H2B + slot * 384 + (off ^ ((slot & 7) << 4))) = make_uint2(w0, w1);
            }
        }
    }

    // prefetch fc1 frags (waves 0,1; nt = wave)
    uint4 afc[6];
    if (wave < 2) {
        #pragma unroll
        for (int kk = 0; kk < 6; ++kk) afc[kk] = fr[(15 + wave * 6 + kk) * 64 + l];
    }

    __syncthreads();

    // fc1: rows = fc cols (regs), cols = 16 samples (slot = m)
    if (wave < 2) {
        const int nt = wave;
        f32x4 acc;
        #pragma unroll
        for (int r = 0; r < 4; ++r) acc[r] = wsf[WS_B3 + (nt * 4 + r) * 64 + l];
        #pragma unroll
        for (int kk = 0; kk < 6; ++kk) {
            uint4 bb = *(const uint4*)(L + H2B + m * 384 +
                                       ((kk * 64 + ch * 16) ^ ((m & 7) << 4)));
            acc = __builtin_amdgcn_mfma_f32_16x16x32_f16(asH(afc[kk]), asH(bb), acc, 0, 0, 0);
        }
        unsigned int w0 = pkr(acc[0], acc[1]);
        unsigned int w1 = pkr(acc[2], acc[3]);
        *(uint2*)(L + H3B + m * 64 + ((nt * 32 + ch * 8) ^ ((m & 3) << 4))) =
            make_uint2(w0, w1);
    }

    __syncthreads();

    // fc2: wave 0 only, 1 MFMA for all 16 samples
    if (wave == 0) {
        uint4 aw = fr[27 * 64 + l];
        uint4 bb = *(const uint4*)(L + H3B + m * 64 +
                                   ((ch * 16) ^ ((m & 3) << 4)));
        f32x4 acc;
        #pragma unroll
        for (int r = 0; r < 4; ++r) acc[r] = wsf[WS_B4 + r * 64 + l];
        acc = __builtin_amdgcn_mfma_f32_16x16x32_f16(asH(aw), asH(bb), acc, 0, 0, 0);
        {
            float* op = out + (size_t)(sblk + m) * 10 + 4 * ch;
            if (ch < 2) {
                *(float2*)op       = make_float2(acc[0], acc[1]);
                *(float2*)(op + 2) = make_float2(acc[2], acc[3]);
            } else if (ch == 2) {
                *(float2*)op       = make_float2(acc[0], acc[1]);
            }
        }
    }
}

extern "C" void kernel_launch(void* const* d_in, const int* in_sizes, int n_in,
                              void* d_out, int out_size, void* d_ws, size_t ws_size,
                              hipStream_t stream) {
    const float* x    = (const float*)d_in[0];
    const float* H1w  = (const float*)d_in[1];
    const float* H1b  = (const float*)d_in[2];
    const float* H2w  = (const float*)d_in[3];
    const float* H2b  = (const float*)d_in[4];
    const float* H3w  = (const float*)d_in[5];
    const float* H3b  = (const float*)d_in[6];
    const float* outw = (const float*)d_in[7];
    const float* outb = (const float*)d_in[8];
    float* outp = (float*)d_out;
    unsigned int* ws = (unsigned int*)d_ws;

    build_tables<<<30, 256, 0, stream>>>(H1w, H1b, H2w, H2b, H3w, H3b, outw, outb, ws);

    const int B = in_sizes[0] / 256;          // 131072
    const int blocks = B / 16;                // 8192
    modernnet_mfma<<<blocks, 512, 0, stream>>>(x, ws, outp);
}

// Round 15
// 91.963 us; speedup vs baseline: 3.6286x; 3.6286x over previous
//
#include <hip/hip_runtime.h>
#include <hip/hip_fp16.h>

typedef _Float16 f16x8 __attribute__((ext_vector_type(8)));
typedef float f32x4 __attribute__((ext_vector_type(4)));

union U4H8 { uint4 u; f16x8 h; };
__device__ inline f16x8 asH(uint4 u){ U4H8 x; x.u = u; return x.h; }
__device__ inline unsigned int pk(float a, float b){
    __half2 h = __floats2half2_rn(a, b);
    union { __half2 h; unsigned int u; } c; c.h = h; return c.u;
}
__device__ inline unsigned int pkr(float a, float b){
    return pk(fmaxf(a, 0.f), fmaxf(b, 0.f));
}
__device__ inline unsigned short h16(float a){
    union { __half h; unsigned short s; } c; c.h = __float2half(a); return c.s;
}

// ws dword layout: frags uint4[28][64] = dwords [0,7168);
// b1f f32[16][64] @7168 | b2f f32[4][64] @8192 | b3f f32[8][64] @8448 |
// b4f f32[4][64] @8960 ; end 9216 dwords (36 KiB).
#define NFRAG 28
#define WS_B1 7168
#define WS_B2 8192
#define WS_B3 8448
#define WS_B4 8960

// frag fi: 0-1 conv1 (k=kh*8+kw, rows=oc); 2-14 conv2 (k=tap*16+ic, rows=oc);
//          15-26 fc1 (nt*6+kk, k=pos*12+oc2, rows=fc-col); 27 fc2 (rows=logit)
__global__ __launch_bounds__(256) void build_tables(
    const float* __restrict__ H1w, const float* __restrict__ H1b,
    const float* __restrict__ H2w, const float* __restrict__ H2b,
    const float* __restrict__ H3w, const float* __restrict__ H3b,
    const float* __restrict__ outw, const float* __restrict__ outb,
    unsigned int* __restrict__ ws)
{
    const int t = threadIdx.x, b = blockIdx.x;
    float* wsf = (float*)ws;

    if (b < NFRAG) {
        if (t < 64) {
            const int lane = t, ch = lane >> 4, oc = lane & 15;
            const int fi = b;
            unsigned short us[8];
            for (int j = 0; j < 8; ++j) {
                float w = 0.f;
                if (fi < 2) {                         // conv1
                    int kh = fi * 4 + ch;
                    if (kh < 5 && j < 5 && oc < 12) w = H1w[oc * 25 + kh * 5 + j];
                } else if (fi < 15) {                 // conv2 channels-last
                    int kk = fi - 2;
                    int tap = kk * 2 + (ch >> 1);
                    int ic = (ch & 1) * 8 + j;
                    if (tap < 25 && oc < 12) {
                        int kh = tap / 5, kw = tap % 5;
                        int q = oc >> 2, icl = -1;
                        if (q == 0)      { if (ic < 8) icl = ic; }
                        else if (q == 1) { if (ic >= 4 && ic < 12) icl = ic - 4; }
                        else             { if (ic < 4) icl = ic;
                                           else if (ic >= 8 && ic < 12) icl = ic - 4; }
                        if (icl >= 0) w = H2w[((oc * 8 + icl) * 5 + kh) * 5 + kw];
                    }
                } else if (fi < 27) {                 // fc1 (k = pos*12+oc2)
                    int idx = fi - 15, nt = idx / 6, kk = idx % 6;
                    int k = kk * 32 + ch * 8 + j;     // 0..191
                    int pos = k / 12, oc2 = k % 12;
                    int col = nt * 16 + oc;
                    if (col < 30) w = H3w[(oc2 * 16 + pos) * 30 + col];
                } else {                              // fc2
                    int k = ch * 8 + j;
                    if (k < 30 && oc < 10) w = outw[k * 10 + oc];
                }
                us[j] = h16(w);
            }
            uint4 u;
            u.x = us[0] | ((unsigned int)us[1] << 16);
            u.y = us[2] | ((unsigned int)us[3] << 16);
            u.z = us[4] | ((unsigned int)us[5] << 16);
            u.w = us[6] | ((unsigned int)us[7] << 16);
            ((uint4*)ws)[fi * 64 + lane] = u;
        }
    } else if (b == NFRAG) {        // b1f: entry e=tt*4+r, lane(ch,m); oc=4ch+r
        for (int idx = t; idx < 1024; idx += 256) {
            int e = idx >> 6, l2 = idx & 63;
            int tt = e >> 2, r = e & 3;
            int oc = 4 * (l2 >> 4) + r, m2 = l2 & 15;
            int oh = 2 * tt + (m2 >> 3), ow = m2 & 7;
            float v = 0.f;
            if (oc < 12) {
                v = H1b[oc * 64 + oh * 8 + ow];
                for (int kh = 0; kh < 5; ++kh)
                    for (int kw = 0; kw < 5; ++kw) {
                        int rr = 2 * oh + kh, cc = 2 * ow + kw;
                        if (rr < 2 || rr >= 18 || cc < 2 || cc >= 18)
                            v -= H1w[oc * 25 + kh * 5 + kw];
                    }
            }
            wsf[WS_B1 + e * 64 + l2] = v;
        }
    } else {                        // b2f + b3f + b4f
        {
            int e = t >> 6, l2 = t & 63;
            int oc = 4 * (l2 >> 4) + e, m2 = l2 & 15;
            int oh = m2 >> 2, ow = m2 & 3;
            float v = 0.f;
            if (oc < 12) {
                v = H2b[oc * 16 + oh * 4 + ow];
                for (int icl = 0; icl < 8; ++icl)
                    for (int kh = 0; kh < 5; ++kh)
                        for (int kw = 0; kw < 5; ++kw) {
                            int rr = 2 * oh + kh - 2, cc = 2 * ow + kw - 2;
                            if (rr < 0 || rr >= 8 || cc < 0 || cc >= 8)
                                v -= H2w[((oc * 8 + icl) * 5 + kh) * 5 + kw];
                        }
            }
            wsf[WS_B2 + e * 64 + l2] = v;
        }
        for (int i = t; i < 512; i += 256) {    // b3f: e = nt*4+r
            int e = i >> 6, l2 = i & 63;
            int nt = e >> 2, r = e & 3, ch = l2 >> 4;
            int j = nt * 16 + 4 * ch + r;
            wsf[WS_B3 + e * 64 + l2] = (j < 30) ? H3b[j] : 0.f;
        }
        {                                        // b4f: e = r
            int e = t >> 6, l2 = t & 63, ch = l2 >> 4;
            int j = 4 * ch + e;
            wsf[WS_B4 + e * 64 + l2] = (j < 10) ? outb[j] : 0.f;
        }
    }
}

// ---------------- main kernel: 512 threads, 16 samples, 8 waves ----------------
// R13 structure (best: 94.7 us dispatch), refined:
//   - ring-zero runs ONCE (hoisted right after the conv1 rd reads): both
//     samples' xs are staged up front and all rd reads complete before the
//     s-loop, and nothing writes ring positions afterwards (epilogues write
//     interior positions only) -> pass-1 ring-zero was redundant.
// LDS (45568 B -> 3 blocks/CU = 24 waves/CU):
//   wave regions @ w*4608: h1c [144 pos][16 ch] half, XOR-swizzled;
//     xs0 overlays bytes 0-960 (dead after rd reads).
//   xs1 pool @ 36864 + w*960: sample1 padded input; dead after rd reads ->
//     reused for the wave's two h2 slots (s*384).
//   h3 @ 44544: 16 slots x 64 B.
// launch_bounds (512,4): cap 128 VGPR (R10 lesson: tighter caps -> 2 GB spill;
// R14 lesson: scattered per-lane global loads -> 427 MB HBM fetch. Coalesced
// xs staging through LDS is load-bearing.)
#define XS1B 36864
#define H3B3 44544
__global__ __launch_bounds__(512, 4) void modernnet_mfma(
    const float* __restrict__ x, const unsigned int* __restrict__ ws,
    float* __restrict__ out)
{
    __shared__ uint4 lds4[2848];
    char* L = (char*)lds4;
    const int t = threadIdx.x, wave = t >> 6, l = t & 63;
    const int ch = l >> 4, m = l & 15;
    char* base = L + wave * 4608;
    char* x1b  = L + XS1B + wave * 960;
    const int sblk = blockIdx.x * 16;
    const int s0 = sblk + wave * 2;

    const uint4* fr = (const uint4*)ws;
    const float* wsf = (const float*)ws;

    // hoisted global x loads: lanes 0-31 sample0, lanes 32-63 sample1
    const float* xp = x + (size_t)s0 * 256 + l * 8;
    float4 xv0 = *(const float4*)xp;
    float4 xv1 = *(const float4*)(xp + 4);

    // conv1 weight + bias frags
    uint4 c1b0 = fr[0 * 64 + l], c1b1 = fr[1 * 64 + l];
    f32x4 b1f[4];
    #pragma unroll
    for (int tt = 0; tt < 4; ++tt)
        #pragma unroll
        for (int r = 0; r < 4; ++r) b1f[tt][r] = wsf[WS_B1 + (tt * 4 + r) * 64 + l];

    // conv2 per-lane read offsets (16-ch swizzled layout)
    int c2off[13];
    {
        const int mb = 24 * (m >> 2) + 2 * (m & 3);
        const int hb = (ch & 1) << 4;
        const int sel = (ch >> 1) & 1;
        #pragma unroll
        for (int kk = 0; kk < 13; ++kk) {
            const int t0 = 2 * kk;
            const int t1 = (2 * kk + 1 <= 24) ? 2 * kk + 1 : 24;
            const int p0 = (t0 / 5) * 12 + (t0 % 5);
            const int p1 = (t1 / 5) * 12 + (t1 % 5);
            int pos = mb + (sel ? p1 : p0);
            c2off[kk] = ((pos << 5) + hb) ^ ((pos & 12) << 2);
        }
    }

    // zero xs0 (region bytes 0-960) and xs1 (pool bytes 0-960)
    {
        uint4 z; z.x = z.y = z.z = z.w = 0u;
        if (l < 60) {
            ((uint4*)base)[l] = z;
            ((uint4*)x1b)[l] = z;
        }
    }

    // write x interiors -> f16, rows 2-17 cols 2-17 (sample by lane half)
    {
        int sI = l >> 5, idx = l & 31;
        int r = idx >> 1, c = (idx & 1) * 8;
        char* dst = (sI ? x1b : base) + (r + 2) * 48 + (c + 2) * 2;
        ((unsigned int*)dst)[0] = pk(xv0.x, xv0.y);
        ((unsigned int*)dst)[1] = pk(xv0.z, xv0.w);
        ((unsigned int*)dst)[2] = pk(xv1.x, xv1.y);
        ((unsigned int*)dst)[3] = pk(xv1.z, xv1.w);
    }

    // conv1 reads for BOTH samples (xs0/xs1 dead after this block)
    uint4 rd[2][5];
    #pragma unroll
    for (int s = 0; s < 2; ++s)
        #pragma unroll
        for (int i = 0; i < 5; ++i) {
            const int cho = (i < 4) ? ch * 48 : 0;   // rd[4]: wave-uniform row
            const char* src = (s ? x1b : base)
                + (2 * i + (m >> 3)) * 96 + (m & 7) * 4 + cho;
            const unsigned int* p = (const unsigned int*)src;
            rd[s][i] = make_uint4(p[0], p[1], p[2], p[3]);
        }

    // ring-zero ONCE, hoisted here (only hazard was the xs0 overlay, now dead;
    // issues LDS writes while the conv1 MFMAs below occupy the matrix pipe)
    {
        uint4 z; z.x = z.y = z.z = z.w = 0u;
        #pragma unroll
        for (int k2 = 0; k2 < 3; ++k2) {
            int idx = l + k2 * 64;          // 0..159
            if (idx < 160) {
                int pi = idx >> 1, half = idx & 1;
                int pos;
                if (pi < 24) pos = pi;
                else if (pi < 48) pos = pi + 96;
                else {
                    int q = pi - 48;
                    int c = q & 3; c = (c < 2) ? c : c + 8;
                    pos = (2 + (q >> 2)) * 12 + c;
                }
                int off = ((pos << 5) + (half << 4)) ^ ((pos & 12) << 2);
                *(uint4*)(base + off) = z;
            }
        }
    }

    // conv1 MFMAs: tile tt uses rd[s][tt] (kh0-3) + rd[s][tt+1] (kh4; only
    // ch=0 lanes carry nonzero c1b1 weights, rows = 4tt+2h+4 = correct).
    f32x4 acc1[8];
    #pragma unroll
    for (int i = 0; i < 8; ++i) {
        const int s = i >> 2, tt = i & 3;
        f32x4 acc = b1f[tt];
        acc = __builtin_amdgcn_mfma_f32_16x16x32_f16(asH(c1b0), asH(rd[s][tt]), acc, 0, 0, 0);
        acc = __builtin_amdgcn_mfma_f32_16x16x32_f16(asH(c1b1), asH(rd[s][tt + 1]), acc, 0, 0, 0);
        acc1[i] = acc;
    }

    // conv2 weights + bias
    uint4 c2b[13];
    #pragma unroll
    for (int kk = 0; kk < 13; ++kk) c2b[kk] = fr[(2 + kk) * 64 + l];
    f32x4 b2f;
    #pragma unroll
    for (int r = 0; r < 4; ++r) b2f[r] = wsf[WS_B2 + r * 64 + l];

    // -------- sample passes through the single region --------
    #pragma unroll
    for (int s = 0; s < 2; ++s) {
        // conv1 epilogue for sample s (interior positions only; pass-1 writes
        // queue behind pass-0 conv2 reads via same-wave LDS ordering)
        #pragma unroll
        for (int tt = 0; tt < 4; ++tt) {
            const f32x4 acc = acc1[s * 4 + tt];
            const int pos = (2 * tt + (m >> 3) + 2) * 12 + (m & 7) + 2;
            const int off = ((pos << 5) + ch * 8) ^ ((pos & 12) << 2);
            unsigned int w0 = pkr(acc[0], acc[1]);
            unsigned int w1 = pkr(acc[2], acc[3]);
            *(uint2*)(base + off) = make_uint2(w0, w1);
        }

        // conv2: 13 b128 reads + 13 MFMA; h2 slot lives in the xs1 pool
        {
            f32x4 a = b2f;
            #pragma unroll
            for (int kk = 0; kk < 13; ++kk) {
                uint4 r0 = *(const uint4*)(base + c2off[kk]);
                a = __builtin_amdgcn_mfma_f32_16x16x32_f16(asH(c2b[kk]), asH(r0), a, 0, 0, 0);
            }
            if (ch < 3) {
                const int slot = wave * 2 + s;
                const int off = m * 24 + ch * 8;
                unsigned int w0 = pkr(a[0], a[1]);
                unsigned int w1 = pkr(a[2], a[3]);
                *(uint2*)(x1b + s * 384 + (off ^ ((slot & 7) << 4))) = make_uint2(w0, w1);
            }
        }
    }

    // prefetch fc1 frags (waves 0,1; nt = wave)
    uint4 afc[6];
    if (wave < 2) {
        #pragma unroll
        for (int kk = 0; kk < 6; ++kk) afc[kk] = fr[(15 + wave * 6 + kk) * 64 + l];
    }

    __syncthreads();

    // fc1: rows = fc cols (regs), cols = 16 samples (slot = m, pool read)
    if (wave < 2) {
        const int nt = wave;
        f32x4 acc;
        #pragma unroll
        for (int r = 0; r < 4; ++r) acc[r] = wsf[WS_B3 + (nt * 4 + r) * 64 + l];
        #pragma unroll
        for (int kk = 0; kk < 6; ++kk) {
            uint4 bb = *(const uint4*)(L + XS1B + (m >> 1) * 960 + (m & 1) * 384 +
                                       ((kk * 64 + ch * 16) ^ ((m & 7) << 4)));
            acc = __builtin_amdgcn_mfma_f32_16x16x32_f16(asH(afc[kk]), asH(bb), acc, 0, 0, 0);
        }
        // h3[sample m][j]
        unsigned int w0 = pkr(acc[0], acc[1]);
        unsigned int w1 = pkr(acc[2], acc[3]);
        *(uint2*)(L + H3B3 + m * 64 + ((nt * 32 + ch * 8) ^ ((m & 3) << 4))) =
            make_uint2(w0, w1);
    }

    __syncthreads();

    // fc2: wave 0 only, 1 MFMA for all 16 samples
    if (wave == 0) {
        uint4 aw = fr[27 * 64 + l];
        uint4 bb = *(const uint4*)(L + H3B3 + m * 64 +
                                   ((ch * 16) ^ ((m & 3) << 4)));
        f32x4 acc;
        #pragma unroll
        for (int r = 0; r < 4; ++r) acc[r] = wsf[WS_B4 + r * 64 + l];
        acc = __builtin_amdgcn_mfma_f32_16x16x32_f16(asH(aw), asH(bb), acc, 0, 0, 0);
        {
            float* op = out + (size_t)(sblk + m) * 10 + 4 * ch;
            if (ch < 2) {
                *(float2*)op       = make_float2(acc[0], acc[1]);
                *(float2*)(op + 2) = make_float2(acc[2], acc[3]);
            } else if (ch == 2) {
                *(float2*)op       = make_float2(acc[0], acc[1]);
            }
        }
    }
}

extern "C" void kernel_launch(void* const* d_in, const int* in_sizes, int n_in,
                              void* d_out, int out_size, void* d_ws, size_t ws_size,
                              hipStream_t stream) {
    const float* x    = (const float*)d_in[0];
    const float* H1w  = (const float*)d_in[1];
    const float* H1b  = (const float*)d_in[2];
    const float* H2w  = (const float*)d_in[3];
    const float* H2b  = (const float*)d_in[4];
    const float* H3w  = (const float*)d_in[5];
    const float* H3b  = (const float*)d_in[6];
    const float* outw = (const float*)d_in[7];
    const float* outb = (const float*)d_in[8];
    float* outp = (float*)d_out;
    unsigned int* ws = (unsigned int*)d_ws;

    build_tables<<<30, 256, 0, stream>>>(H1w, H1b, H2w, H2b, H3w, H3b, outw, outb, ws);

    const int B = in_sizes[0] / 256;          // 131072
    const int blocks = B / 16;                // 8192
    modernnet_mfma<<<blocks, 512, 0, stream>>>(x, ws, outp);
}